// Round 12
// baseline (120.387 us; speedup 1.0000x reference)
//
#include <hip/hip_runtime.h>

static constexpr int N = 100000;
static constexpr int E = 3200000;
static constexpr int BUKSHIFT = 8;
static constexpr int BUKSZ = 1 << BUKSHIFT;             // 256 nodes / bucket
static constexpr int BUKMASK = BUKSZ - 1;
static constexpr int NBUK = (N + BUKSZ - 1) / BUKSZ;    // 391
static constexpr int CAP = 12288;                        // slots per bucket region
static constexpr int GSTRIDE = 16;                       // pad gofs to 64B lines
static constexpr int SC_CHUNK = 2048;
static constexpr int SC_T = 512;
static constexpr int SC_BLOCKS = (E + SC_CHUNK - 1) / SC_CHUNK;  // 1563
static constexpr int S = 4;                              // sub-blocks per bucket
static constexpr int NP2 = (N + 1023) / 1024;            // 98 partial blocks

// ws (4B): binned[NBUK*CAP] | gofs[NBUK*GSTRIDE] | degg[N] | accg[N] | tpg[N] | tng[N]
//          | dinv[N] | y1[N] | m[N] | partials[NP2*16]

__global__ void k_init(int* __restrict__ gofs, int* __restrict__ degg,
                       float* __restrict__ accg, float* __restrict__ tpg,
                       float* __restrict__ tng) {
    int i = blockIdx.x * blockDim.x + threadIdx.x;
    if (i < N) { degg[i] = 0; accg[i] = 0.f; tpg[i] = 0.f; tng[i] = 0.f; }
    if (i < NBUK) gofs[i * GSTRIDE] = i * CAP;
}

// Minimal scatter: 4-replica LDS hist -> one reservation per (block,bucket) ->
// direct computed-address global writes. 2048 edges/block for high residency.
__global__ __launch_bounds__(SC_T) void k_scatter(const int4* __restrict__ rows4,
                                                  const int4* __restrict__ cols4,
                                                  int* __restrict__ gofs,
                                                  int* __restrict__ binned) {
    __shared__ int hist[4 * NBUK];
    __shared__ int gbase[NBUK];

    const int tid = threadIdx.x;
    const int g = tid >> 7;          // 4 replica groups of 128 threads
    for (int i = tid; i < 4 * NBUK; i += SC_T) hist[i] = 0;
    __syncthreads();

    const int nI4 = E / 4;
    const int ia = blockIdx.x * (SC_CHUNK / 4) + tid;
    const bool va = ia < nI4;
    int4 ra, ca;
    if (va) { ra = rows4[ia]; ca = cols4[ia]; }

    if (va) {
        atomicAdd(&hist[g * NBUK + (ca.x >> BUKSHIFT)], 1);
        atomicAdd(&hist[g * NBUK + (ca.y >> BUKSHIFT)], 1);
        atomicAdd(&hist[g * NBUK + (ca.z >> BUKSHIFT)], 1);
        atomicAdd(&hist[g * NBUK + (ca.w >> BUKSHIFT)], 1);
    }
    __syncthreads();

    if (tid < NBUK) {
        int h0 = hist[0 * NBUK + tid], h1 = hist[1 * NBUK + tid];
        int h2 = hist[2 * NBUK + tid], h3 = hist[3 * NBUK + tid];
        hist[0 * NBUK + tid] = 0;
        hist[1 * NBUK + tid] = h0;
        hist[2 * NBUK + tid] = h0 + h1;
        hist[3 * NBUK + tid] = h0 + h1 + h2;
        int c = h0 + h1 + h2 + h3;
        gbase[tid] = c ? atomicAdd(&gofs[tid * GSTRIDE], c) : 0;
    }
    __syncthreads();

    if (va) {
        int b, off;
        b = ca.x >> BUKSHIFT; off = atomicAdd(&hist[g * NBUK + b], 1); binned[gbase[b] + off] = (ra.x << BUKSHIFT) | (ca.x & BUKMASK);
        b = ca.y >> BUKSHIFT; off = atomicAdd(&hist[g * NBUK + b], 1); binned[gbase[b] + off] = (ra.y << BUKSHIFT) | (ca.y & BUKMASK);
        b = ca.z >> BUKSHIFT; off = atomicAdd(&hist[g * NBUK + b], 1); binned[gbase[b] + off] = (ra.z << BUKSHIFT) | (ca.z & BUKMASK);
        b = ca.w >> BUKSHIFT; off = atomicAdd(&hist[g * NBUK + b], 1); binned[gbase[b] + off] = (ra.w << BUKSHIFT) | (ca.w & BUKMASK);
    }
}

// ---- pass A kernels: grid = NBUK*S, block (bucket b, sub s) handles segment slice ----

__global__ __launch_bounds__(SC_T) void k_degA(const int* __restrict__ binned,
                                               const int* __restrict__ gofs,
                                               int* __restrict__ degg) {
    __shared__ int cnt[4][BUKSZ];
    const int tid = threadIdx.x;
    for (int i = tid; i < 4 * BUKSZ; i += SC_T) (&cnt[0][0])[i] = 0;
    __syncthreads();
    const int b = blockIdx.x >> 2, s = blockIdx.x & 3, g = tid >> 7;
    const int s0 = b * CAP;
    const int n = gofs[b * GSTRIDE] - s0;
    const int n4 = n >> 2;
    const int q0 = (n4 * s) / S, q1 = (n4 * (s + 1)) / S;
    const int4* b4 = (const int4*)(binned + s0);
    for (int i = q0 + tid; i < q1; i += SC_T) {
        int4 p = b4[i];
        atomicAdd(&cnt[g][p.x & BUKMASK], 1);
        atomicAdd(&cnt[g][p.y & BUKMASK], 1);
        atomicAdd(&cnt[g][p.z & BUKMASK], 1);
        atomicAdd(&cnt[g][p.w & BUKMASK], 1);
    }
    if (s == S - 1 && tid < (n & 3)) atomicAdd(&cnt[g][binned[s0 + (n4 << 2) + tid] & BUKMASK], 1);
    __syncthreads();
    if (tid < BUKSZ) {
        int v = (b << BUKSHIFT) + tid;
        if (v < N) {
            int c = cnt[0][tid] + cnt[1][tid] + cnt[2][tid] + cnt[3][tid];
            if (c) atomicAdd(&degg[v], c);
        }
    }
}

__global__ void k_degF(const int* __restrict__ degg, const float* __restrict__ x,
                       float* __restrict__ dinv, float* __restrict__ y1) {
    int v = blockIdx.x * blockDim.x + threadIdx.x;
    if (v < N) {
        float d = rsqrtf(1.0f + (float)degg[v]);
        dinv[v] = d;
        y1[v] = d * x[v];
    }
}

__global__ __launch_bounds__(SC_T) void k_acc1A(const int* __restrict__ binned,
                                                const int* __restrict__ gofs,
                                                const float* __restrict__ y1,
                                                float* __restrict__ accg) {
    __shared__ float acc[4][BUKSZ];
    const int tid = threadIdx.x;
    for (int i = tid; i < 4 * BUKSZ; i += SC_T) (&acc[0][0])[i] = 0.f;
    __syncthreads();
    const int b = blockIdx.x >> 2, s = blockIdx.x & 3, g = tid >> 7;
    const int s0 = b * CAP;
    const int n = gofs[b * GSTRIDE] - s0;
    const int n4 = n >> 2;
    const int q0 = (n4 * s) / S, q1 = (n4 * (s + 1)) / S;
    const int4* b4 = (const int4*)(binned + s0);
    for (int i = q0 + tid; i < q1; i += SC_T) {
        int4 p = b4[i];
        atomicAdd(&acc[g][p.x & BUKMASK], y1[p.x >> BUKSHIFT]);
        atomicAdd(&acc[g][p.y & BUKMASK], y1[p.y >> BUKSHIFT]);
        atomicAdd(&acc[g][p.z & BUKMASK], y1[p.z >> BUKSHIFT]);
        atomicAdd(&acc[g][p.w & BUKMASK], y1[p.w >> BUKSHIFT]);
    }
    if (s == S - 1 && tid < (n & 3)) {
        int p = binned[s0 + (n4 << 2) + tid];
        atomicAdd(&acc[g][p & BUKMASK], y1[p >> BUKSHIFT]);
    }
    __syncthreads();
    if (tid < BUKSZ) {
        int v = (b << BUKSHIFT) + tid;
        if (v < N) {
            float a = acc[0][tid] + acc[1][tid] + acc[2][tid] + acc[3][tid];
            if (a != 0.f) atomicAdd(&accg[v], a);
        }
    }
}

__global__ void k_acc1F(const float* __restrict__ accg, const float* __restrict__ dinv,
                        const float* __restrict__ y1, float* __restrict__ m) {
    int v = blockIdx.x * blockDim.x + threadIdx.x;
    if (v < N) {
        float d = dinv[v];
        float s = d * accg[v] + d * y1[v];
        m[v] = d * s;
    }
}

__global__ __launch_bounds__(SC_T) void k_acc2A(const int* __restrict__ binned,
                                                const int* __restrict__ gofs,
                                                const float* __restrict__ m,
                                                float* __restrict__ tpg,
                                                float* __restrict__ tng) {
    __shared__ float tp[4][BUKSZ], tn[4][BUKSZ];
    const int tid = threadIdx.x;
    for (int i = tid; i < 4 * BUKSZ; i += SC_T) { (&tp[0][0])[i] = 0.f; (&tn[0][0])[i] = 0.f; }
    __syncthreads();
    const int b = blockIdx.x >> 2, s = blockIdx.x & 3, g = tid >> 7;
    const int s0 = b * CAP;
    const int n = gofs[b * GSTRIDE] - s0;
    const int n4 = n >> 2;
    const int q0 = (n4 * s) / S, q1 = (n4 * (s + 1)) / S;
    const int4* b4 = (const int4*)(binned + s0);
    for (int i = q0 + tid; i < q1; i += SC_T) {
        int4 p = b4[i];
        float v0 = m[p.x >> BUKSHIFT], v1 = m[p.y >> BUKSHIFT];
        float v2 = m[p.z >> BUKSHIFT], v3 = m[p.w >> BUKSHIFT];
        atomicAdd(v0 >= 0.f ? &tp[g][p.x & BUKMASK] : &tn[g][p.x & BUKMASK], v0);
        atomicAdd(v1 >= 0.f ? &tp[g][p.y & BUKMASK] : &tn[g][p.y & BUKMASK], v1);
        atomicAdd(v2 >= 0.f ? &tp[g][p.z & BUKMASK] : &tn[g][p.z & BUKMASK], v2);
        atomicAdd(v3 >= 0.f ? &tp[g][p.w & BUKMASK] : &tn[g][p.w & BUKMASK], v3);
    }
    if (s == S - 1 && tid < (n & 3)) {
        int p = binned[s0 + (n4 << 2) + tid];
        float val = m[p >> BUKSHIFT];
        atomicAdd(val >= 0.f ? &tp[g][p & BUKMASK] : &tn[g][p & BUKMASK], val);
    }
    __syncthreads();
    if (tid < BUKSZ) {
        int v = (b << BUKSHIFT) + tid;
        if (v < N) {
            float a = tp[0][tid] + tp[1][tid] + tp[2][tid] + tp[3][tid];
            float c = tn[0][tid] + tn[1][tid] + tn[2][tid] + tn[3][tid];
            if (a != 0.f) atomicAdd(&tpg[v], a);
            if (c != 0.f) atomicAdd(&tng[v], c);
        }
    }
}

// per-node h2 -> per-block partial column sums (1024 threads, NP2 blocks)
__global__ __launch_bounds__(1024) void k_acc2F(const float* __restrict__ tpg,
                                                const float* __restrict__ tng,
                                                const float* __restrict__ m,
                                                const float* __restrict__ dinv,
                                                const float* __restrict__ W1,
                                                const float* __restrict__ W2,
                                                float* __restrict__ partials) {
    __shared__ float sP[16], sM[16], sAcc[16];
    const int tid = threadIdx.x;
    if (tid < 16) {
        float p = 0.f, q = 0.f;
        for (int k = 0; k < 16; ++k) {
            float w1 = W1[k];
            float w2 = W2[k * 16 + tid];
            p += fmaxf(w1, 0.f) * w2;
            q += fminf(w1, 0.f) * w2;
        }
        sP[tid] = p; sM[tid] = q; sAcc[tid] = 0.f;
    }
    __syncthreads();
    const int v = blockIdx.x * 1024 + tid;
    float alpha = 0.f, beta = 0.f;
    if (v < N) {
        float d = dinv[v], mv = m[v];
        alpha = d * tpg[v];
        beta  = d * tng[v];
        float self = d * mv;
        if (mv >= 0.f) alpha += self; else beta += self;
    }
    const int lane = tid & 63;
    for (int j = 0; j < 16; ++j) {
        float h = fmaxf(alpha * sP[j] + beta * sM[j], 0.f);
        #pragma unroll
        for (int off = 32; off > 0; off >>= 1) h += __shfl_down(h, off);
        if (lane == 0 && h != 0.f) atomicAdd(&sAcc[j], h);
    }
    __syncthreads();
    if (tid < 16) partials[blockIdx.x * 16 + tid] = sAcc[tid];
}

// reduce partials[NP2][16] -> mean -> out = g @ W3 + b
__global__ void k_out(const float* __restrict__ partials, const float* __restrict__ W3,
                      const float* __restrict__ b, float* __restrict__ out) {
    __shared__ float s[16][16];
    int j = threadIdx.x & 15;
    int g = threadIdx.x >> 4;
    float acc = 0.f;
    for (int blk = g; blk < NP2; blk += 16) acc += partials[blk * 16 + j];
    s[g][j] = acc;
    __syncthreads();
    if (threadIdx.x < 16) {
        float tot = 0.f;
        #pragma unroll
        for (int gg = 0; gg < 16; ++gg) tot += s[gg][threadIdx.x];
        s[0][threadIdx.x] = tot * (1.0f / (float)N);
    }
    __syncthreads();
    if (threadIdx.x < 11) {
        float acc2 = b[threadIdx.x];
        #pragma unroll
        for (int k = 0; k < 16; ++k) acc2 += s[0][k] * W3[k * 11 + threadIdx.x];
        out[threadIdx.x] = acc2;
    }
}

extern "C" void kernel_launch(void* const* d_in, const int* in_sizes, int n_in,
                              void* d_out, int out_size, void* d_ws, size_t ws_size,
                              hipStream_t stream) {
    const float* x  = (const float*)d_in[0];
    const int*   ei = (const int*)d_in[1];   // [2*E]: rows then cols (int32)
    const float* W1 = (const float*)d_in[2];
    const float* W2 = (const float*)d_in[3];
    const float* W3 = (const float*)d_in[4];
    const float* b  = (const float*)d_in[5];
    float* out = (float*)d_out;

    int*   wsi      = (int*)d_ws;
    int*   binned   = wsi;                                      // NBUK*CAP
    int*   gofs     = wsi + (size_t)NBUK * CAP;                 // NBUK*GSTRIDE
    int*   degg     = gofs + NBUK * GSTRIDE;                    // N
    float* accg     = (float*)(degg + N);                       // N
    float* tpg      = accg + N;                                 // N
    float* tng      = tpg + N;                                  // N
    float* dinv     = tng + N;                                  // N
    float* y1       = dinv + N;                                 // N
    float* m        = y1 + N;                                   // N
    float* partials = m + N;                                    // NP2*16

    const int4* rows4 = (const int4*)ei;
    const int4* cols4 = (const int4*)(ei + E);

    k_init   <<<(N + 511) / 512, 512, 0, stream>>>(gofs, degg, accg, tpg, tng);
    k_scatter<<<SC_BLOCKS, SC_T, 0, stream>>>(rows4, cols4, gofs, binned);
    k_degA   <<<NBUK * S, SC_T, 0, stream>>>(binned, gofs, degg);
    k_degF   <<<(N + 511) / 512, 512, 0, stream>>>(degg, x, dinv, y1);
    k_acc1A  <<<NBUK * S, SC_T, 0, stream>>>(binned, gofs, y1, accg);
    k_acc1F  <<<(N + 511) / 512, 512, 0, stream>>>(accg, dinv, y1, m);
    k_acc2A  <<<NBUK * S, SC_T, 0, stream>>>(binned, gofs, m, tpg, tng);
    k_acc2F  <<<NP2, 1024, 0, stream>>>(tpg, tng, m, dinv, W1, W2, partials);
    k_out    <<<1, 256, 0, stream>>>(partials, W3, b, out);
}